// Round 17
// baseline (365.218 us; speedup 1.0000x reference)
//
#include <hip/hip_runtime.h>
#include <math.h>

#define D_DIM 128
#define H_DIM 256
#define W_DIM 256
#define HW (H_DIM * W_DIM)
#define HW4 (HW / 4)
#define NIMG 2
#define NPI (D_DIM * HW)
#define NTOT (NIMG * NPI)

#define TDZ 16
#define TH 16
#define TW 64

#define AW4R 18  // real aS chunks/row: chunk c -> gx = x0-4+4c (x0-4 .. x0+67)
#define AW4 19   // padded aS row stride
#define AH 20    // aS rows: gy = y0-2 .. y0+17
#define EW4R 17  // real eT chunks/row: chunk c -> gx = x0-2+4c (x0-2 .. x0+65)
#define EW4 19   // padded eT row stride
#define EH 18    // eT rows: gy = y0-1 .. y0+16

#define NLOADLIN (AH * AW4)   // 380 padded-linear load slots
#define NLOADP 384            // rounded to 6 full waves

#define NUM_ITER 20
#define STOP_THRESH 1e-4

__device__ __forceinline__ float min3f(float a, float b, float c) { return fminf(fminf(a, b), c); }
__device__ __forceinline__ float max3f(float a, float b, float c) { return fmaxf(fmaxf(a, b), c); }
__device__ __forceinline__ float leaky(float x) { return fmaxf(x, 0.01f * x); }

// lane L receives lane L+1's value within each 16-lane DPP row (row_shl:1).
__device__ __forceinline__ float dpp_shl1(float v) {
    int i = __float_as_int(v);
    int r = __builtin_amdgcn_update_dpp(i, i, 0x101, 0xF, 0xF, false);
    return __int_as_float(r);
}

#define BAR_FULL() do { asm volatile("s_waitcnt vmcnt(0) lgkmcnt(0)" ::: "memory"); \
                        __builtin_amdgcn_s_barrier(); \
                        __builtin_amdgcn_sched_barrier(0); } while (0)
#define BAR_VM4()  do { asm volatile("s_waitcnt vmcnt(4) lgkmcnt(0)" ::: "memory"); \
                        __builtin_amdgcn_s_barrier(); \
                        __builtin_amdgcn_sched_barrier(0); } while (0)
#define BAR_VM2()  do { asm volatile("s_waitcnt vmcnt(2) lgkmcnt(0)" ::: "memory"); \
                        __builtin_amdgcn_s_barrier(); \
                        __builtin_amdgcn_sched_barrier(0); } while (0)
#define BAR_LDS() do { asm volatile("s_waitcnt lgkmcnt(0)" ::: "memory"); \
                       __builtin_amdgcn_s_barrier(); \
                       __builtin_amdgcn_sched_barrier(0); } while (0)

#define GLOAD_LDS(gp, lp) \
    __builtin_amdgcn_global_load_lds((const __attribute__((address_space(1))) unsigned int*)(gp), \
                                     (__attribute__((address_space(3))) unsigned int*)(lp), 16, 0, 0)

__global__ void init_slots(double* slots) {
    int t = threadIdx.x;
    if (t < 32) slots[t] = 0.0;
    if (t >= 32 && t < 36) ((float*)(slots + 32))[t - 32] = INFINITY;  // 16B +INF cell
}

// R16 + DPP-ized erosion: erode items DPP-row-aligned (row=t>>4, wq=t&15; rows
// 16,17 as item1 on t<32). Own aS column read (3 b128) + vertical min3 in regs;
// neighbor column's vertical min via row_shl:1 DPP. Boundary lanes (wq==15)
// read aS chunks 16,17 and also produce eT chunk 16 (own D-chain).
__global__ __launch_bounds__(256) void skel_step(
    const float* __restrict__ a_in,
    float* __restrict__ a_out,
    float* __restrict__ skel,
    double* __restrict__ slots,
    int step)
{
    __shared__ float4 aS4[4][NLOADP];  // 24576 B (4 slice slots, gload dest)
    __shared__ float4 eT4[2][EH * EW4];// 10944 B (padded rows)
    __shared__ float wsum[4];
    __shared__ int s_active;

    const int t = threadIdx.x;

    if (t == 0) {
        int act = 1;
        for (int j = 1; j < step; ++j)
            if (!(slots[j] >= STOP_THRESH * (double)NTOT)) { act = 0; break; }
        s_active = act;
    }
    __syncthreads();
    if (!s_active) return;

    const float* infp = (const float*)(slots + 32);

    // XCD-aware swizzle: grid (4,16,16) = 1024 blocks.
    const int lid = blockIdx.x + 4 * (blockIdx.y + 16 * blockIdx.z);
    const int swz = (lid & 7) * 128 + (lid >> 3);
    const int bx = swz & 3;
    const int by = (swz >> 2) & 15;
    const int zz = swz >> 6;
    const int bz = zz & 7, img = zz >> 3;
    const int x0 = bx * TW, y0 = by * TH, z0 = bz * TDZ;

    const float* in = a_in + (size_t)img * NPI;
    float4* aout4 = (float4*)(a_out + (size_t)img * NPI);
    float4* sk4 = (float4*)(skel + (size_t)img * NPI);

    // ---- load items in PADDED-linear order: q0 = t, q1 = t+256 (t<128) ----
    int lOff0; bool lVal0;
    {
        int lr = t / AW4, lc = t - lr * AW4;
        int gy = y0 - 2 + lr, gx = x0 - 4 + 4 * lc;
        lVal0 = (lc < AW4R) && ((unsigned)gy < H_DIM) && ((unsigned)gx <= (unsigned)(W_DIM - 4));
        lOff0 = gy * W_DIM + gx;
    }
    const bool hasL1 = t < 128;          // wave-uniform
    int lOff1 = 0; bool lVal1 = false;
    if (hasL1) {
        int q = t + 256;
        int lr = q / AW4, lc = q - lr * AW4;
        int gy = y0 - 2 + lr, gx = x0 - 4 + 4 * lc;
        lVal1 = (q < NLOADLIN) && (lc < AW4R) && ((unsigned)gy < H_DIM)
                && ((unsigned)gx <= (unsigned)(W_DIM - 4));
        lOff1 = gy * W_DIM + gx;
    }
    const int wbase = (t >> 6) << 6;     // wave-uniform LDS base (element units)

    // ---- erode items, DPP-aligned ----
    const int wq = t & 15;
    const bool isB = (wq == 15);
    // item0: rows 0..15
    const int er0 = t >> 4;
    const int eRd0 = er0 * AW4 + wq;
    const int eWr0 = er0 * EW4 + wq;
    bool k0A, k0B, k0C, k0D, b0A, b0B, b0C, b0D;
    {
        int gy = y0 - 1 + er0;
        bool gok = (unsigned)gy < H_DIM;
        int g = x0 - 2 + 4 * wq;
        k0A = gok && ((unsigned)(g + 0) < W_DIM);
        k0B = gok && ((unsigned)(g + 1) < W_DIM);
        k0C = gok && ((unsigned)(g + 2) < W_DIM);
        k0D = gok && ((unsigned)(g + 3) < W_DIM);
        int gb = x0 + 62;   // chunk 16
        b0A = gok && ((unsigned)(gb + 0) < W_DIM);
        b0B = gok && ((unsigned)(gb + 1) < W_DIM);
        b0C = gok && ((unsigned)(gb + 2) < W_DIM);
        b0D = gok && ((unsigned)(gb + 3) < W_DIM);
    }
    // item1: rows 16..17 on t<32
    const bool hasE1 = t < 32;
    const int er1 = 16 + (t >> 4);       // valid for t<32
    const int eRd1 = er1 * AW4 + wq;
    const int eWr1 = er1 * EW4 + wq;
    bool k1A = false, k1B = false, k1C = false, k1D = false;
    bool b1A = false, b1B = false, b1C = false, b1D = false;
    if (hasE1) {
        int gy = y0 - 1 + er1;
        bool gok = (unsigned)gy < H_DIM;
        int g = x0 - 2 + 4 * wq;
        k1A = gok && ((unsigned)(g + 0) < W_DIM);
        k1B = gok && ((unsigned)(g + 1) < W_DIM);
        k1C = gok && ((unsigned)(g + 2) < W_DIM);
        k1D = gok && ((unsigned)(g + 3) < W_DIM);
        int gb = x0 + 62;
        b1A = gok && ((unsigned)(gb + 0) < W_DIM);
        b1B = gok && ((unsigned)(gb + 1) < W_DIM);
        b1C = gok && ((unsigned)(gb + 2) < W_DIM);
        b1D = gok && ((unsigned)(gb + 3) < W_DIM);
    }

    // ---- out item ----
    const int oh = t >> 4;
    const int oRd = oh * EW4 + wq;
    const int oAc = (oh + 2) * AW4 + wq + 1;
    size_t ob = ((size_t)z0 * HW + (size_t)(y0 + oh) * W_DIM + (size_t)x0) / 4 + wq;

    const float INF = INFINITY;
    const float4 ninf4 = make_float4(-INF, -INF, -INF, -INF);
    const float4 inf4 = make_float4(INF, INF, INF, INF);
    // rolling chains (advance by 2 per pair)
    float4 e0P2 = inf4, e0P1 = inf4, e0P2b = inf4, e0P1b = inf4;
    float4 e1P2 = inf4, e1P1 = inf4, e1P2b = inf4, e1P1b = inf4;
    float4 xP2 = ninf4, xP1 = ninf4;
    float4 acP2 = make_float4(0, 0, 0, 0), acP1 = acP2, ecP = acP2;
    float lsum = 0.f;

    // ---- prologue: issue slices 0,1 into slots 0,1 ----
    for (int s = 0; s < 2; ++s) {
        int z = z0 - 2 + s;
        bool zok = (unsigned)z < D_DIM;
        const float* p = in + (size_t)z * HW;
        const float* s0 = (zok && lVal0) ? (p + lOff0) : infp;
        GLOAD_LDS(s0, &aS4[s][wbase]);
        if (hasL1) {
            const float* s1 = (zok && lVal1) ? (p + lOff1) : infp;
            GLOAD_LDS(s1, &aS4[s][256 + wbase]);
        }
    }

    // One DPP erode item. Executed uniformly by its thread set; lane wq==15
    // overrides DPP results with direct chunk-16/17 reads and also emits
    // eT chunk 16. P2/P1 = D-chain for own chunk; P2B/P1B = chain for chunk 16.
    #define ERODE_DPP(SLOT, ZPV, DO_E, ETI, RD, WR, P2, P1, P2B, P1B,              \
                      kA, kB, kC, kD, bA, bB, bC, bD)                              \
    do {                                                                           \
        const float4* s_ = aS4[SLOT];                                              \
        float4 A0 = s_[RD], A1 = s_[RD + AW4], A2 = s_[RD + 2 * AW4];              \
        float4 va;                                                                 \
        va.x = min3f(A0.x, A1.x, A2.x); va.y = min3f(A0.y, A1.y, A2.y);            \
        va.z = min3f(A0.z, A1.z, A2.z); va.w = min3f(A0.w, A1.w, A2.w);            \
        float4 va16 = inf4, va17 = inf4;                                           \
        if (isB) {                                                                 \
            float4 B0 = s_[RD + 1], B1 = s_[RD + 1 + AW4], B2 = s_[RD + 1 + 2 * AW4]; \
            va16.x = min3f(B0.x, B1.x, B2.x); va16.y = min3f(B0.y, B1.y, B2.y);    \
            va16.z = min3f(B0.z, B1.z, B2.z); va16.w = min3f(B0.w, B1.w, B2.w);    \
            float4 C0 = s_[RD + 2], C1 = s_[RD + 2 + AW4], C2 = s_[RD + 2 + 2 * AW4]; \
            va17.x = min3f(C0.x, C1.x, C2.x); va17.y = min3f(C0.y, C1.y, C2.y);    \
            va17.z = min3f(C0.z, C1.z, C2.z);                                      \
        }                                                                          \
        float nx = dpp_shl1(va.x), ny = dpp_shl1(va.y), nz = dpp_shl1(va.z);       \
        float vbx = isB ? va16.x : nx;                                             \
        float vby = isB ? va16.y : ny;                                             \
        float vbz = isB ? va16.z : nz;                                             \
        float4 mC;                                                                 \
        mC.x = min3f(va.y, va.z, va.w); mC.y = min3f(va.z, va.w, vbx);             \
        mC.z = min3f(va.w, vbx, vby);   mC.w = min3f(vbx, vby, vbz);               \
        if ((DO_E) && (ZPV)) {                                                     \
            float4 e;                                                              \
            e.x = kA ? min3f(P2.x, P1.x, mC.x) : -INF;                             \
            e.y = kB ? min3f(P2.y, P1.y, mC.y) : -INF;                             \
            e.z = kC ? min3f(P2.z, P1.z, mC.z) : -INF;                             \
            e.w = kD ? min3f(P2.w, P1.w, mC.w) : -INF;                             \
            eT4[ETI][WR] = e;                                                      \
        }                                                                          \
        P2 = P1; P1 = mC;                                                          \
        if (isB) {                                                                 \
            float4 mCb;                                                            \
            mCb.x = min3f(va16.y, va16.z, va16.w);                                 \
            mCb.y = min3f(va16.z, va16.w, va17.x);                                 \
            mCb.z = min3f(va16.w, va17.x, va17.y);                                 \
            mCb.w = min3f(va17.x, va17.y, va17.z);                                 \
            if ((DO_E) && (ZPV)) {                                                 \
                float4 e;                                                          \
                e.x = bA ? min3f(P2B.x, P1B.x, mCb.x) : -INF;                      \
                e.y = bB ? min3f(P2B.y, P1B.y, mCb.y) : -INF;                      \
                e.z = bC ? min3f(P2B.z, P1B.z, mCb.z) : -INF;                      \
                e.w = bD ? min3f(P2B.w, P1B.w, mCb.w) : -INF;                      \
                eT4[ETI][WR + 1] = e;                                              \
            }                                                                      \
            P2B = P1B; P1B = mCb;                                                  \
        }                                                                          \
    } while (0)

    // DPP dilation (from R16): 3 own-column reads + divergent 17th column.
    #define MAX9(ETI, xCv, ecv)                                                    \
    do {                                                                           \
        const float4* eP_ = eT4[ETI];                                              \
        float4 A0 = eP_[oRd], A1 = eP_[oRd + EW4], A2 = eP_[oRd + 2 * EW4];        \
        float4 B0, B1, B2;                                                         \
        if (isB) {                                                                 \
            B0 = eP_[oRd + 1]; B1 = eP_[oRd + EW4 + 1]; B2 = eP_[oRd + 2 * EW4 + 1]; \
        }                                                                          \
        float4 vm;                                                                 \
        vm.x = max3f(A0.x, A1.x, A2.x); vm.y = max3f(A0.y, A1.y, A2.y);            \
        vm.z = max3f(A0.z, A1.z, A2.z); vm.w = max3f(A0.w, A1.w, A2.w);            \
        float sx = dpp_shl1(vm.x), sy = dpp_shl1(vm.y), sz = dpp_shl1(vm.z);       \
        float c1x = dpp_shl1(A1.x), c1y = dpp_shl1(A1.y);                          \
        float bvx = max3f(B0.x, B1.x, B2.x);                                       \
        float bvy = max3f(B0.y, B1.y, B2.y);                                       \
        float bvz = max3f(B0.z, B1.z, B2.z);                                       \
        float nbx = isB ? bvx : sx;                                                \
        float nby = isB ? bvy : sy;                                                \
        float nbz = isB ? bvz : sz;                                                \
        xCv.x = max3f(vm.y, vm.z, vm.w);                                           \
        xCv.y = max3f(vm.z, vm.w, nbx);                                            \
        xCv.z = max3f(vm.w, nbx, nby);                                             \
        xCv.w = max3f(nbx, nby, nbz);                                              \
        ecv.x = A1.z; ecv.y = A1.w;                                                \
        ecv.z = isB ? B1.x : c1x;                                                  \
        ecv.w = isB ? B1.y : c1y;                                                  \
    } while (0)

    for (int k = 0; k < (TDZ + 4) / 2; ++k) {
        const int i0 = 2 * k, i1 = 2 * k + 1;
        const int slot0 = i0 & 3, slot1 = i1 & 3;

        if (k < 3) { BAR_FULL(); }
        else if (step == NUM_ITER) { BAR_VM2(); }
        else { BAR_VM4(); }

        // early skel prefetch (oldest VMEM of the pair)
        float4 ggPre0, ggPre1;
        if (step > 0 && i0 >= 4) { ggPre0 = sk4[ob]; ggPre1 = sk4[ob + HW4]; }
        __builtin_amdgcn_sched_barrier(0);

        // issue next pair (slices 2k+2, 2k+3) into the opposite slots
        if (k <= (TDZ + 4) / 2 - 2) {
            for (int s = 0; s < 2; ++s) {
                int z = z0 + 2 * k + s;
                bool zok = (unsigned)z < D_DIM;
                const float* p = in + (size_t)z * HW;
                const float* s0 = (zok && lVal0) ? (p + lOff0) : infp;
                GLOAD_LDS(s0, &aS4[(i0 + 2 + s) & 3][wbase]);
                if (hasL1) {
                    const float* s1 = (zok && lVal1) ? (p + lOff1) : infp;
                    GLOAD_LDS(s1, &aS4[(i0 + 2 + s) & 3][256 + wbase]);
                }
            }
        }
        __builtin_amdgcn_sched_barrier(0);

        const bool zp0 = (unsigned)(z0 - 3 + i0) < D_DIM;
        const bool zp1 = (unsigned)(z0 - 3 + i1) < D_DIM;
        const bool doE = (i0 >= 2);

        // ---- erode both slices -> eT4[0], eT4[1] ----
        ERODE_DPP(slot0, zp0, doE, 0, eRd0, eWr0, e0P2, e0P1, e0P2b, e0P1b,
                  k0A, k0B, k0C, k0D, b0A, b0B, b0C, b0D);
        if (hasE1)
            ERODE_DPP(slot0, zp0, doE, 0, eRd1, eWr1, e1P2, e1P1, e1P2b, e1P1b,
                      k1A, k1B, k1C, k1D, b1A, b1B, b1C, b1D);
        // slice 1: chains advanced again
        ERODE_DPP(slot1, zp1, (i1 >= 2), 1, eRd0, eWr0, e0P2, e0P1, e0P2b, e0P1b,
                  k0A, k0B, k0C, k0D, b0A, b0B, b0C, b0D);
        if (hasE1)
            ERODE_DPP(slot1, zp1, (i1 >= 2), 1, eRd1, eWr1, e1P2, e1P1, e1P2b, e1P1b,
                      k1A, k1B, k1C, k1D, b1A, b1B, b1C, b1D);

        // a-centers for both slices (issued pre-B2; aS4 pair stable)
        const float4 aCn0 = aS4[slot0][oAc];
        const float4 aCn1 = aS4[slot1][oAc];

        BAR_LDS();  // B2: eT4 ready (vmcnt NOT drained — next pair in flight)

        // ---- out both slices ----
        {
            float4 xC0, ecB0, xC1, ecB1;
            if (doE && zp0) { MAX9(0, xC0, ecB0); } else { xC0 = ninf4; ecB0 = ninf4; }
            if (doE && zp1) { MAX9(1, xC1, ecB1); } else { xC1 = ninf4; ecB1 = ninf4; }

            if (i0 >= 4) {
                {
                    float4 dl;
                    dl.x = leaky(acP2.x - max3f(xP2.x, xP1.x, xC0.x));
                    dl.y = leaky(acP2.y - max3f(xP2.y, xP1.y, xC0.y));
                    dl.z = leaky(acP2.z - max3f(xP2.z, xP1.z, xC0.z));
                    dl.w = leaky(acP2.w - max3f(xP2.w, xP1.w, xC0.w));
                    if (step < NUM_ITER) aout4[ob] = ecP;
                    if (step == 0) {
                        sk4[ob] = dl;
                    } else {
                        float4 gg = ggPre0, up, gn;
                        up.x = leaky(dl.x - gg.x * dl.x); gn.x = gg.x + up.x;
                        up.y = leaky(dl.y - gg.y * dl.y); gn.y = gg.y + up.y;
                        up.z = leaky(dl.z - gg.z * dl.z); gn.z = gg.z + up.z;
                        up.w = leaky(dl.w - gg.w * dl.w); gn.w = gg.w + up.w;
                        sk4[ob] = gn;
                        if (step == 1)
                            lsum += fabsf(gn.x) + fabsf(gn.y) + fabsf(gn.z) + fabsf(gn.w);
                        else
                            lsum += fabsf(up.x) + fabsf(up.y) + fabsf(up.z) + fabsf(up.w);
                    }
                }
                {
                    float4 dl;
                    dl.x = leaky(acP1.x - max3f(xP1.x, xC0.x, xC1.x));
                    dl.y = leaky(acP1.y - max3f(xP1.y, xC0.y, xC1.y));
                    dl.z = leaky(acP1.z - max3f(xP1.z, xC0.z, xC1.z));
                    dl.w = leaky(acP1.w - max3f(xP1.w, xC0.w, xC1.w));
                    if (step < NUM_ITER) aout4[ob + HW4] = ecB0;
                    if (step == 0) {
                        sk4[ob + HW4] = dl;
                    } else {
                        float4 gg = ggPre1, up, gn;
                        up.x = leaky(dl.x - gg.x * dl.x); gn.x = gg.x + up.x;
                        up.y = leaky(dl.y - gg.y * dl.y); gn.y = gg.y + up.y;
                        up.z = leaky(dl.z - gg.z * dl.z); gn.z = gg.z + up.z;
                        up.w = leaky(dl.w - gg.w * dl.w); gn.w = gg.w + up.w;
                        sk4[ob + HW4] = gn;
                        if (step == 1)
                            lsum += fabsf(gn.x) + fabsf(gn.y) + fabsf(gn.z) + fabsf(gn.w);
                        else
                            lsum += fabsf(up.x) + fabsf(up.y) + fabsf(up.z) + fabsf(up.w);
                    }
                }
                ob += 2 * HW4;
            }
            xP2 = xC0; xP1 = xC1;
            acP2 = aCn0; acP1 = aCn1;
            ecP = ecB1;
        }
    }

    #undef ERODE_DPP
    #undef MAX9

    // dn reduction: one double atomic per block
    if (step > 0) {
        #pragma unroll
        for (int off = 32; off > 0; off >>= 1)
            lsum += __shfl_down(lsum, off, 64);
        const int lane = t & 63, wid = t >> 6;
        if (lane == 0) wsum[wid] = lsum;
        __syncthreads();
        if (t == 0) {
            float b = wsum[0] + wsum[1] + wsum[2] + wsum[3];
            atomicAdd(&slots[step], (double)b);
        }
    }
}

extern "C" void kernel_launch(void* const* d_in, const int* in_sizes, int n_in,
                              void* d_out, int out_size, void* d_ws, size_t ws_size,
                              hipStream_t stream) {
    const float* img = (const float*)d_in[0];
    float* out = (float*)d_out;
    float* buf0 = (float*)d_ws;
    float* buf1 = buf0 + NTOT;
    double* slots = (double*)(buf1 + NTOT);

    init_slots<<<1, 64, 0, stream>>>(slots);

    dim3 grid(W_DIM / TW, H_DIM / TH, (D_DIM / TDZ) * NIMG);
    for (int s = 0; s <= NUM_ITER; ++s) {
        const float* ain = (s == 0) ? img : ((s & 1) ? buf0 : buf1);
        float* aout = (s & 1) ? buf1 : buf0;
        skel_step<<<grid, 256, 0, stream>>>(ain, aout, out, slots, s);
    }
}

// Round 19
// 335.520 us; speedup vs baseline: 1.0885x; 1.0885x over previous
//
#include <hip/hip_runtime.h>
#include <math.h>

#define D_DIM 128
#define H_DIM 256
#define W_DIM 256
#define HW (H_DIM * W_DIM)
#define HW4 (HW / 4)
#define NIMG 2
#define NPI (D_DIM * HW)
#define NTOT (NIMG * NPI)

#define TDZ 16
#define TH 16
#define TW 64

#define AW4R 18  // real aS chunks/row: chunk c -> gx = x0-4+4c (x0-4 .. x0+67)
#define AW4 19   // padded aS row stride
#define AH 20    // aS rows: gy = y0-2 .. y0+17
#define EW4R 17  // real eT chunks/row: chunk c -> gx = x0-2+4c (x0-2 .. x0+65)
#define EW4 19   // padded eT row stride
#define EH 18    // eT rows: gy = y0-1 .. y0+16

#define NLOADLIN (AH * AW4)   // 380 padded-linear load slots
#define NLOADP 384            // rounded to 6 full waves
#define NERO  (EH * EW4R)     // 306 real erode items
#define NOUT  (TH * (TW/4))   // 256

#define NUM_ITER 20
#define STOP_THRESH 1e-4

__device__ __forceinline__ float min3f(float a, float b, float c) { return fminf(fminf(a, b), c); }
__device__ __forceinline__ float max3f(float a, float b, float c) { return fmaxf(fmaxf(a, b), c); }
__device__ __forceinline__ float leaky(float x) { return fmaxf(x, 0.01f * x); }

// lane L receives lane L+1's value within each 16-lane DPP row (row_shl:1).
// Must be executed by ALL lanes (uniform control flow) so source data exists.
__device__ __forceinline__ float dpp_shl1(float v) {
    int i = __float_as_int(v);
    int r = __builtin_amdgcn_update_dpp(i, i, 0x101, 0xF, 0xF, false);
    return __int_as_float(r);
}

// B1 variants: drain gloads but leave prior-pair stores in flight where safe.
#define BAR_FULL() do { asm volatile("s_waitcnt vmcnt(0) lgkmcnt(0)" ::: "memory"); \
                        __builtin_amdgcn_s_barrier(); \
                        __builtin_amdgcn_sched_barrier(0); } while (0)
#define BAR_VM4()  do { asm volatile("s_waitcnt vmcnt(4) lgkmcnt(0)" ::: "memory"); \
                        __builtin_amdgcn_s_barrier(); \
                        __builtin_amdgcn_sched_barrier(0); } while (0)
#define BAR_VM2()  do { asm volatile("s_waitcnt vmcnt(2) lgkmcnt(0)" ::: "memory"); \
                        __builtin_amdgcn_s_barrier(); \
                        __builtin_amdgcn_sched_barrier(0); } while (0)
// B2: LDS-only drain — keeps global_load_lds for the next pair in flight
#define BAR_LDS() do { asm volatile("s_waitcnt lgkmcnt(0)" ::: "memory"); \
                       __builtin_amdgcn_s_barrier(); \
                       __builtin_amdgcn_sched_barrier(0); } while (0)

#define GLOAD_LDS(gp, lp) \
    __builtin_amdgcn_global_load_lds((const __attribute__((address_space(1))) unsigned int*)(gp), \
                                     (__attribute__((address_space(3))) unsigned int*)(lp), 16, 0, 0)

__global__ void init_slots(double* slots) {
    int t = threadIdx.x;
    if (t < 32) slots[t] = 0.0;
    if (t >= 32 && t < 36) ((float*)(slots + 32))[t - 32] = INFINITY;  // 16B +INF cell
}

// R16 structure (pair-unrolled, DPP sliding-window dilation): out phase reads
// only its own eT column (3 b128) and gets the neighbor column's vertical max
// via row_shl:1 DPP. Boundary lanes (wq==15) read the 17th column. Gating is
// per-thread uniform (no LDS broadcast / barrier).
__global__ __launch_bounds__(256) void skel_step(
    const float* __restrict__ a_in,
    float* __restrict__ a_out,
    float* __restrict__ skel,
    double* __restrict__ slots,
    int step)
{
    __shared__ float4 aS4[4][NLOADP];  // 24576 B (4 slice slots, gload dest)
    __shared__ float4 eT4[2][EH * EW4];// 10944 B (padded rows)
    __shared__ float wsum[4];

    const int t = threadIdx.x;

    // gating: uniform per-thread check (slots[] reads are scalar/L2-cached)
    {
        int act = 1;
        for (int j = 1; j < step; ++j)
            if (!(slots[j] >= STOP_THRESH * (double)NTOT)) { act = 0; break; }
        if (!act) return;
    }

    const float* infp = (const float*)(slots + 32);

    // XCD-aware swizzle: grid (4,16,16) = 1024 blocks; XCD k owns swz in
    // [128k,128(k+1)) = full xy coverage of 2 adjacent z-slabs.
    const int lid = blockIdx.x + 4 * (blockIdx.y + 16 * blockIdx.z);
    const int swz = (lid & 7) * 128 + (lid >> 3);
    const int bx = swz & 3;
    const int by = (swz >> 2) & 15;
    const int zz = swz >> 6;           // 0..15
    const int bz = zz & 7, img = zz >> 3;
    const int x0 = bx * TW, y0 = by * TH, z0 = bz * TDZ;

    const float* in = a_in + (size_t)img * NPI;
    float4* aout4 = (float4*)(a_out + (size_t)img * NPI);
    float4* sk4 = (float4*)(skel + (size_t)img * NPI);

    // ---- load items in PADDED-linear order: q0 = t, q1 = t+256 (t<128) ----
    int lOff0; bool lVal0;
    {
        int lr = t / AW4, lc = t - lr * AW4;
        int gy = y0 - 2 + lr, gx = x0 - 4 + 4 * lc;
        lVal0 = (lc < AW4R) && ((unsigned)gy < H_DIM) && ((unsigned)gx <= (unsigned)(W_DIM - 4));
        lOff0 = gy * W_DIM + gx;
    }
    const bool hasL1 = t < 128;          // wave-uniform
    int lOff1 = 0; bool lVal1 = false;
    if (hasL1) {
        int q = t + 256;
        int lr = q / AW4, lc = q - lr * AW4;
        int gy = y0 - 2 + lr, gx = x0 - 4 + 4 * lc;
        lVal1 = (q < NLOADLIN) && (lc < AW4R) && ((unsigned)gy < H_DIM)
                && ((unsigned)gx <= (unsigned)(W_DIM - 4));
        lOff1 = gy * W_DIM + gx;
    }
    const int wbase = (t >> 6) << 6;     // wave-uniform LDS base (element units)

    // ---- erode items (real 17-wide grid; padded stride-19 addressing) ----
    int eRd0, eWr0; bool sA0, sB0, sC0, sD0;
    {
        int mh = t / EW4R, ej = t - mh * EW4R;
        eRd0 = mh * AW4 + ej;
        eWr0 = mh * EW4 + ej;
        int gy = y0 - 1 + mh;
        bool gok = (unsigned)gy < H_DIM;
        int gxb = x0 - 2 + 4 * ej;
        sA0 = gok && ((unsigned)(gxb + 0) < W_DIM);
        sB0 = gok && ((unsigned)(gxb + 1) < W_DIM);
        sC0 = gok && ((unsigned)(gxb + 2) < W_DIM);
        sD0 = gok && ((unsigned)(gxb + 3) < W_DIM);
    }
    const bool hasE1 = t < (NERO - 256);    // t < 50
    int eRd1 = 0, eWr1 = 0; bool sA1 = false, sB1 = false, sC1 = false, sD1 = false;
    if (hasE1) {
        int q = t + 256;
        int mh = q / EW4R, ej = q - mh * EW4R;
        eRd1 = mh * AW4 + ej;
        eWr1 = mh * EW4 + ej;
        int gy = y0 - 1 + mh;
        bool gok = (unsigned)gy < H_DIM;
        int gxb = x0 - 2 + 4 * ej;
        sA1 = gok && ((unsigned)(gxb + 0) < W_DIM);
        sB1 = gok && ((unsigned)(gxb + 1) < W_DIM);
        sC1 = gok && ((unsigned)(gxb + 2) < W_DIM);
        sD1 = gok && ((unsigned)(gxb + 3) < W_DIM);
    }

    // ---- out item ----
    const int oh = t >> 4, wq = t & 15;
    const bool isB = (wq == 15);         // boundary lane: owns the 17th column
    const int oRd = oh * EW4 + wq;
    const int oAc = (oh + 2) * AW4 + wq + 1;
    size_t ob = ((size_t)z0 * HW + (size_t)(y0 + oh) * W_DIM + (size_t)x0) / 4 + wq;

    const float INF = INFINITY;
    const float4 ninf4 = make_float4(-INF, -INF, -INF, -INF);
    const float4 inf4 = make_float4(INF, INF, INF, INF);
    // rolling chains (advance by 2 per pair)
    float4 m0P2 = inf4, m0P1 = inf4, m1P2 = inf4, m1P1 = inf4;
    float4 xP2 = ninf4, xP1 = ninf4;
    float4 acP2 = make_float4(0, 0, 0, 0), acP1 = acP2, ecP = acP2;
    float lsum = 0.f;

    // ---- prologue: issue slices 0,1 into slots 0,1 ----
    for (int s = 0; s < 2; ++s) {
        int z = z0 - 2 + s;
        bool zok = (unsigned)z < D_DIM;
        const float* p = in + (size_t)z * HW;
        const float* s0 = (zok && lVal0) ? (p + lOff0) : infp;
        GLOAD_LDS(s0, &aS4[s][wbase]);
        if (hasL1) {
            const float* s1 = (zok && lVal1) ? (p + lOff1) : infp;
            GLOAD_LDS(s1, &aS4[s][256 + wbase]);
        }
    }

    #define ERODE_SLICE(SLOT, ZPV, DO_E, ETI, mP2v, mP1v, m1P2v, m1P1v)            \
    do {                                                                           \
        const float4* s_ = aS4[SLOT];                                              \
        float4 a0 = s_[eRd0],           b0 = s_[eRd0 + 1];                         \
        float4 a1 = s_[eRd0 + AW4],     b1 = s_[eRd0 + AW4 + 1];                   \
        float4 a2 = s_[eRd0 + 2 * AW4], b2 = s_[eRd0 + 2 * AW4 + 1];               \
        float4 va, vb, mC;                                                         \
        va.x = min3f(a0.x, a1.x, a2.x); va.y = min3f(a0.y, a1.y, a2.y);            \
        va.z = min3f(a0.z, a1.z, a2.z); va.w = min3f(a0.w, a1.w, a2.w);            \
        vb.x = min3f(b0.x, b1.x, b2.x); vb.y = min3f(b0.y, b1.y, b2.y);            \
        vb.z = min3f(b0.z, b1.z, b2.z);                                            \
        mC.x = min3f(va.y, va.z, va.w); mC.y = min3f(va.z, va.w, vb.x);            \
        mC.z = min3f(va.w, vb.x, vb.y); mC.w = min3f(vb.x, vb.y, vb.z);            \
        if ((DO_E) && (ZPV)) {                                                     \
            float4 e;                                                              \
            e.x = sA0 ? min3f(mP2v.x, mP1v.x, mC.x) : -INF;                        \
            e.y = sB0 ? min3f(mP2v.y, mP1v.y, mC.y) : -INF;                        \
            e.z = sC0 ? min3f(mP2v.z, mP1v.z, mC.z) : -INF;                        \
            e.w = sD0 ? min3f(mP2v.w, mP1v.w, mC.w) : -INF;                        \
            eT4[ETI][eWr0] = e;                                                    \
        }                                                                          \
        mP2v = mP1v; mP1v = mC;                                                    \
        if (hasE1) {                                                               \
            float4 c0 = s_[eRd1],           d0 = s_[eRd1 + 1];                     \
            float4 c1 = s_[eRd1 + AW4],     d1 = s_[eRd1 + AW4 + 1];               \
            float4 c2 = s_[eRd1 + 2 * AW4], d2 = s_[eRd1 + 2 * AW4 + 1];           \
            float4 wa, wb, nC;                                                     \
            wa.x = min3f(c0.x, c1.x, c2.x); wa.y = min3f(c0.y, c1.y, c2.y);        \
            wa.z = min3f(c0.z, c1.z, c2.z); wa.w = min3f(c0.w, c1.w, c2.w);        \
            wb.x = min3f(d0.x, d1.x, d2.x); wb.y = min3f(d0.y, d1.y, d2.y);        \
            wb.z = min3f(d0.z, d1.z, d2.z);                                        \
            nC.x = min3f(wa.y, wa.z, wa.w); nC.y = min3f(wa.z, wa.w, wb.x);        \
            nC.z = min3f(wa.w, wb.x, wb.y); nC.w = min3f(wb.x, wb.y, wb.z);        \
            if ((DO_E) && (ZPV)) {                                                 \
                float4 e;                                                          \
                e.x = sA1 ? min3f(m1P2v.x, m1P1v.x, nC.x) : -INF;                  \
                e.y = sB1 ? min3f(m1P2v.y, m1P1v.y, nC.y) : -INF;                  \
                e.z = sC1 ? min3f(m1P2v.z, m1P1v.z, nC.z) : -INF;                  \
                e.w = sD1 ? min3f(m1P2v.w, m1P1v.w, nC.w) : -INF;                  \
                eT4[ETI][eWr1] = e;                                                \
            }                                                                      \
            m1P2v = m1P1v; m1P1v = nC;                                             \
        }                                                                          \
    } while (0)

    // DPP dilation: 3 own-column reads + divergent 17th-column reads on wq==15;
    // neighbor column's vertical max + raw center row via row_shl:1 DPP.
    // NOTE: dpp_shl1 must run in uniform control flow (all 256 lanes).
    #define MAX9(ETI, xCv, ecv)                                                    \
    do {                                                                           \
        const float4* eP_ = eT4[ETI];                                              \
        float4 A0 = eP_[oRd], A1 = eP_[oRd + EW4], A2 = eP_[oRd + 2 * EW4];        \
        float4 B0, B1, B2;                                                         \
        if (isB) {                                                                 \
            B0 = eP_[oRd + 1]; B1 = eP_[oRd + EW4 + 1]; B2 = eP_[oRd + 2 * EW4 + 1]; \
        }                                                                          \
        float4 vm;                                                                 \
        vm.x = max3f(A0.x, A1.x, A2.x); vm.y = max3f(A0.y, A1.y, A2.y);            \
        vm.z = max3f(A0.z, A1.z, A2.z); vm.w = max3f(A0.w, A1.w, A2.w);            \
        float sx = dpp_shl1(vm.x), sy = dpp_shl1(vm.y), sz = dpp_shl1(vm.z);       \
        float c1x = dpp_shl1(A1.x), c1y = dpp_shl1(A1.y);                          \
        float bvx = max3f(B0.x, B1.x, B2.x);                                       \
        float bvy = max3f(B0.y, B1.y, B2.y);                                       \
        float bvz = max3f(B0.z, B1.z, B2.z);                                       \
        float nbx = isB ? bvx : sx;                                                \
        float nby = isB ? bvy : sy;                                                \
        float nbz = isB ? bvz : sz;                                                \
        xCv.x = max3f(vm.y, vm.z, vm.w);                                           \
        xCv.y = max3f(vm.z, vm.w, nbx);                                            \
        xCv.z = max3f(vm.w, nbx, nby);                                             \
        xCv.w = max3f(nbx, nby, nbz);                                              \
        ecv.x = A1.z; ecv.y = A1.w;                                                \
        ecv.z = isB ? B1.x : c1x;                                                  \
        ecv.w = isB ? B1.y : c1y;                                                  \
    } while (0)

    for (int k = 0; k < (TDZ + 4) / 2; ++k) {
        const int i0 = 2 * k, i1 = 2 * k + 1;
        const int slot0 = i0 & 3, slot1 = i1 & 3;

        // B1: pair slices loaded. k<3: only gloads outstanding -> full drain.
        // k>=3: leave prior pair's stores (4; 2 at step 20) in flight.
        if (k < 3) { BAR_FULL(); }
        else if (step == NUM_ITER) { BAR_VM2(); }
        else { BAR_VM4(); }

        // early skel prefetch (oldest VMEM of the pair)
        float4 ggPre0, ggPre1;
        if (step > 0 && i0 >= 4) { ggPre0 = sk4[ob]; ggPre1 = sk4[ob + HW4]; }
        __builtin_amdgcn_sched_barrier(0);

        // issue next pair (slices 2k+2, 2k+3) into the opposite slots
        if (k <= (TDZ + 4) / 2 - 2) {
            for (int s = 0; s < 2; ++s) {
                int z = z0 + 2 * k + s;          // slice 2k+2+s -> z0-2+(2k+2+s)
                bool zok = (unsigned)z < D_DIM;
                const float* p = in + (size_t)z * HW;
                const float* s0 = (zok && lVal0) ? (p + lOff0) : infp;
                GLOAD_LDS(s0, &aS4[(i0 + 2 + s) & 3][wbase]);
                if (hasL1) {
                    const float* s1 = (zok && lVal1) ? (p + lOff1) : infp;
                    GLOAD_LDS(s1, &aS4[(i0 + 2 + s) & 3][256 + wbase]);
                }
            }
        }
        __builtin_amdgcn_sched_barrier(0);

        const bool zp0 = (unsigned)(z0 - 3 + i0) < D_DIM;
        const bool zp1 = (unsigned)(z0 - 3 + i1) < D_DIM;
        const bool doE = (i0 >= 2);

        // ---- erode both slices -> eT4[0], eT4[1] ----
        ERODE_SLICE(slot0, zp0, doE, 0, m0P2, m0P1, m1P2, m1P1);
        ERODE_SLICE(slot1, zp1, (i1 >= 2), 1, m0P2, m0P1, m1P2, m1P1);

        // a-centers for both slices (issued pre-B2; aS4 pair stable)
        const float4 aCn0 = aS4[slot0][oAc];
        const float4 aCn1 = aS4[slot1][oAc];

        BAR_LDS();  // B2: eT4 ready (vmcnt NOT drained — next pair in flight)

        // ---- out both slices ----
        {
            float4 xC0, ecB0, xC1, ecB1;
            if (doE && zp0) { MAX9(0, xC0, ecB0); } else { xC0 = ninf4; ecB0 = ninf4; }
            if (doE && zp1) { MAX9(1, xC1, ecB1); } else { xC1 = ninf4; ecB1 = ninf4; }

            if (i0 >= 4) {
                {
                    float4 dl;
                    dl.x = leaky(acP2.x - max3f(xP2.x, xP1.x, xC0.x));
                    dl.y = leaky(acP2.y - max3f(xP2.y, xP1.y, xC0.y));
                    dl.z = leaky(acP2.z - max3f(xP2.z, xP1.z, xC0.z));
                    dl.w = leaky(acP2.w - max3f(xP2.w, xP1.w, xC0.w));
                    if (step < NUM_ITER) aout4[ob] = ecP;
                    if (step == 0) {
                        sk4[ob] = dl;
                    } else {
                        float4 gg = ggPre0, up, gn;
                        up.x = leaky(dl.x - gg.x * dl.x); gn.x = gg.x + up.x;
                        up.y = leaky(dl.y - gg.y * dl.y); gn.y = gg.y + up.y;
                        up.z = leaky(dl.z - gg.z * dl.z); gn.z = gg.z + up.z;
                        up.w = leaky(dl.w - gg.w * dl.w); gn.w = gg.w + up.w;
                        sk4[ob] = gn;
                        if (step == 1)
                            lsum += fabsf(gn.x) + fabsf(gn.y) + fabsf(gn.z) + fabsf(gn.w);
                        else
                            lsum += fabsf(up.x) + fabsf(up.y) + fabsf(up.z) + fabsf(up.w);
                    }
                }
                {
                    float4 dl;
                    dl.x = leaky(acP1.x - max3f(xP1.x, xC0.x, xC1.x));
                    dl.y = leaky(acP1.y - max3f(xP1.y, xC0.y, xC1.y));
                    dl.z = leaky(acP1.z - max3f(xP1.z, xC0.z, xC1.z));
                    dl.w = leaky(acP1.w - max3f(xP1.w, xC0.w, xC1.w));
                    if (step < NUM_ITER) aout4[ob + HW4] = ecB0;
                    if (step == 0) {
                        sk4[ob + HW4] = dl;
                    } else {
                        float4 gg = ggPre1, up, gn;
                        up.x = leaky(dl.x - gg.x * dl.x); gn.x = gg.x + up.x;
                        up.y = leaky(dl.y - gg.y * dl.y); gn.y = gg.y + up.y;
                        up.z = leaky(dl.z - gg.z * dl.z); gn.z = gg.z + up.z;
                        up.w = leaky(dl.w - gg.w * dl.w); gn.w = gg.w + up.w;
                        sk4[ob + HW4] = gn;
                        if (step == 1)
                            lsum += fabsf(gn.x) + fabsf(gn.y) + fabsf(gn.z) + fabsf(gn.w);
                        else
                            lsum += fabsf(up.x) + fabsf(up.y) + fabsf(up.z) + fabsf(up.w);
                    }
                }
                ob += 2 * HW4;
            }
            xP2 = xC0; xP1 = xC1;
            acP2 = aCn0; acP1 = aCn1;
            ecP = ecB1;
        }
    }

    #undef ERODE_SLICE
    #undef MAX9

    // dn reduction: one double atomic per block
    if (step > 0) {
        #pragma unroll
        for (int off = 32; off > 0; off >>= 1)
            lsum += __shfl_down(lsum, off, 64);
        const int lane = t & 63, wid = t >> 6;
        if (lane == 0) wsum[wid] = lsum;
        __syncthreads();
        if (t == 0) {
            float b = wsum[0] + wsum[1] + wsum[2] + wsum[3];
            atomicAdd(&slots[step], (double)b);
        }
    }
}

extern "C" void kernel_launch(void* const* d_in, const int* in_sizes, int n_in,
                              void* d_out, int out_size, void* d_ws, size_t ws_size,
                              hipStream_t stream) {
    const float* img = (const float*)d_in[0];
    float* out = (float*)d_out;
    float* buf0 = (float*)d_ws;
    float* buf1 = buf0 + NTOT;
    double* slots = (double*)(buf1 + NTOT);

    init_slots<<<1, 64, 0, stream>>>(slots);

    dim3 grid(W_DIM / TW, H_DIM / TH, (D_DIM / TDZ) * NIMG);
    for (int s = 0; s <= NUM_ITER; ++s) {
        const float* ain = (s == 0) ? img : ((s & 1) ? buf0 : buf1);
        float* aout = (s & 1) ? buf1 : buf0;
        skel_step<<<grid, 256, 0, stream>>>(ain, aout, out, slots, s);
    }
}

// Round 20
// 332.122 us; speedup vs baseline: 1.0996x; 1.0102x over previous
//
#include <hip/hip_runtime.h>
#include <math.h>

#define D_DIM 128
#define H_DIM 256
#define W_DIM 256
#define HW (H_DIM * W_DIM)
#define HW4 (HW / 4)
#define NIMG 2
#define NPI (D_DIM * HW)
#define NTOT (NIMG * NPI)

#define TDZ 16
#define TH 16
#define TW 64

#define AW4R 18  // real aS chunks/row: chunk c -> gx = x0-4+4c (x0-4 .. x0+67)
#define AW4 19   // padded aS row stride
#define AH 20    // aS rows: gy = y0-2 .. y0+17
#define EW4R 17  // real eT chunks/row: chunk c -> gx = x0-2+4c (x0-2 .. x0+65)
#define EW4 19   // padded eT row stride
#define EH 18    // eT rows: gy = y0-1 .. y0+16

#define NLOADLIN (AH * AW4)   // 380 padded-linear load slots
#define NLOADP 384            // rounded to 6 full waves
#define NEPAIR ((EH / 2) * EW4R)  // 153 row-pair erode items

#define NUM_ITER 20
#define STOP_THRESH 1e-4

__device__ __forceinline__ float min3f(float a, float b, float c) { return fminf(fminf(a, b), c); }
__device__ __forceinline__ float max3f(float a, float b, float c) { return fmaxf(fmaxf(a, b), c); }
__device__ __forceinline__ float leaky(float x) { return fmaxf(x, 0.01f * x); }

// lane L receives lane L+1's value within each 16-lane DPP row (row_shl:1).
// Must be executed by ALL lanes (uniform control flow) so source data exists.
__device__ __forceinline__ float dpp_shl1(float v) {
    int i = __float_as_int(v);
    int r = __builtin_amdgcn_update_dpp(i, i, 0x101, 0xF, 0xF, false);
    return __int_as_float(r);
}

// B1 variants: drain gloads but leave prior-pair stores in flight where safe.
#define BAR_FULL() do { asm volatile("s_waitcnt vmcnt(0) lgkmcnt(0)" ::: "memory"); \
                        __builtin_amdgcn_s_barrier(); \
                        __builtin_amdgcn_sched_barrier(0); } while (0)
#define BAR_VM4()  do { asm volatile("s_waitcnt vmcnt(4) lgkmcnt(0)" ::: "memory"); \
                        __builtin_amdgcn_s_barrier(); \
                        __builtin_amdgcn_sched_barrier(0); } while (0)
#define BAR_VM2()  do { asm volatile("s_waitcnt vmcnt(2) lgkmcnt(0)" ::: "memory"); \
                        __builtin_amdgcn_s_barrier(); \
                        __builtin_amdgcn_sched_barrier(0); } while (0)
// B2: LDS-only drain — keeps global_load_lds for the next pair in flight
#define BAR_LDS() do { asm volatile("s_waitcnt lgkmcnt(0)" ::: "memory"); \
                       __builtin_amdgcn_s_barrier(); \
                       __builtin_amdgcn_sched_barrier(0); } while (0)

#define GLOAD_LDS(gp, lp) \
    __builtin_amdgcn_global_load_lds((const __attribute__((address_space(1))) unsigned int*)(gp), \
                                     (__attribute__((address_space(3))) unsigned int*)(lp), 16, 0, 0)

__global__ void init_slots(double* slots) {
    int t = threadIdx.x;
    if (t < 32) slots[t] = 0.0;
    if (t >= 32 && t < 36) ((float*)(slots + 32))[t - 32] = INFINITY;  // 16B +INF cell
}

// R19 structure + row-pair erode: each erode item owns eT rows (2rp, 2rp+1) at
// chunk ej — reads 4 aS rows x 2 cols (8 b128) and produces 2 output chunks
// (4 reads/chunk vs 6). No DPP in erode, no tail-item imbalance. Out phase
// keeps the R16 DPP sliding-window dilation.
__global__ __launch_bounds__(256) void skel_step(
    const float* __restrict__ a_in,
    float* __restrict__ a_out,
    float* __restrict__ skel,
    double* __restrict__ slots,
    int step)
{
    __shared__ float4 aS4[4][NLOADP];  // 24576 B (4 slice slots, gload dest)
    __shared__ float4 eT4[2][EH * EW4];// 10944 B (padded rows)
    __shared__ float wsum[4];

    const int t = threadIdx.x;

    // gating: uniform per-thread check (slots[] reads are scalar/L2-cached)
    {
        int act = 1;
        for (int j = 1; j < step; ++j)
            if (!(slots[j] >= STOP_THRESH * (double)NTOT)) { act = 0; break; }
        if (!act) return;
    }

    const float* infp = (const float*)(slots + 32);

    // XCD-aware swizzle: grid (4,16,16) = 1024 blocks; XCD k owns swz in
    // [128k,128(k+1)) = full xy coverage of 2 adjacent z-slabs.
    const int lid = blockIdx.x + 4 * (blockIdx.y + 16 * blockIdx.z);
    const int swz = (lid & 7) * 128 + (lid >> 3);
    const int bx = swz & 3;
    const int by = (swz >> 2) & 15;
    const int zz = swz >> 6;           // 0..15
    const int bz = zz & 7, img = zz >> 3;
    const int x0 = bx * TW, y0 = by * TH, z0 = bz * TDZ;

    const float* in = a_in + (size_t)img * NPI;
    float4* aout4 = (float4*)(a_out + (size_t)img * NPI);
    float4* sk4 = (float4*)(skel + (size_t)img * NPI);

    // ---- load items in PADDED-linear order: q0 = t, q1 = t+256 (t<128) ----
    int lOff0; bool lVal0;
    {
        int lr = t / AW4, lc = t - lr * AW4;
        int gy = y0 - 2 + lr, gx = x0 - 4 + 4 * lc;
        lVal0 = (lc < AW4R) && ((unsigned)gy < H_DIM) && ((unsigned)gx <= (unsigned)(W_DIM - 4));
        lOff0 = gy * W_DIM + gx;
    }
    const bool hasL1 = t < 128;          // wave-uniform
    int lOff1 = 0; bool lVal1 = false;
    if (hasL1) {
        int q = t + 256;
        int lr = q / AW4, lc = q - lr * AW4;
        int gy = y0 - 2 + lr, gx = x0 - 4 + 4 * lc;
        lVal1 = (q < NLOADLIN) && (lc < AW4R) && ((unsigned)gy < H_DIM)
                && ((unsigned)gx <= (unsigned)(W_DIM - 4));
        lOff1 = gy * W_DIM + gx;
    }
    const int wbase = (t >> 6) << 6;     // wave-uniform LDS base (element units)

    // ---- erode items: row-pair (rp, ej), t = rp*17 + ej, t < 153 ----
    const bool isE = t < NEPAIR;
    int eRdP = 0, eWrP = 0;
    bool s0A = false, s0B = false, s0C = false, s0D = false;
    bool s1A = false, s1B = false, s1C = false, s1D = false;
    if (isE) {
        int rp = t / EW4R, ej = t - rp * EW4R;
        int mh0 = 2 * rp;               // eT rows mh0, mh0+1
        eRdP = mh0 * AW4 + ej;          // aS rows mh0..mh0+3, cols ej, ej+1
        eWrP = mh0 * EW4 + ej;
        int gy0e = y0 - 1 + mh0;
        bool g0 = (unsigned)gy0e < H_DIM;
        bool g1 = (unsigned)(gy0e + 1) < H_DIM;
        int gxb = x0 - 2 + 4 * ej;
        bool xA = (unsigned)(gxb + 0) < W_DIM;
        bool xB = (unsigned)(gxb + 1) < W_DIM;
        bool xC = (unsigned)(gxb + 2) < W_DIM;
        bool xD = (unsigned)(gxb + 3) < W_DIM;
        s0A = g0 && xA; s0B = g0 && xB; s0C = g0 && xC; s0D = g0 && xD;
        s1A = g1 && xA; s1B = g1 && xB; s1C = g1 && xC; s1D = g1 && xD;
    }

    // ---- out item ----
    const int oh = t >> 4, wq = t & 15;
    const bool isB = (wq == 15);         // boundary lane: owns the 17th column
    const int oRd = oh * EW4 + wq;
    const int oAc = (oh + 2) * AW4 + wq + 1;
    size_t ob = ((size_t)z0 * HW + (size_t)(y0 + oh) * W_DIM + (size_t)x0) / 4 + wq;

    const float INF = INFINITY;
    const float4 ninf4 = make_float4(-INF, -INF, -INF, -INF);
    const float4 inf4 = make_float4(INF, INF, INF, INF);
    // rolling D-chains: row0 (m0*) and row1 (m1*) of the pair; advance per slice
    float4 m0P2 = inf4, m0P1 = inf4, m1P2 = inf4, m1P1 = inf4;
    float4 xP2 = ninf4, xP1 = ninf4;
    float4 acP2 = make_float4(0, 0, 0, 0), acP1 = acP2, ecP = acP2;
    float lsum = 0.f;

    // ---- prologue: issue slices 0,1 into slots 0,1 ----
    for (int s = 0; s < 2; ++s) {
        int z = z0 - 2 + s;
        bool zok = (unsigned)z < D_DIM;
        const float* p = in + (size_t)z * HW;
        const float* s0 = (zok && lVal0) ? (p + lOff0) : infp;
        GLOAD_LDS(s0, &aS4[s][wbase]);
        if (hasL1) {
            const float* s1 = (zok && lVal1) ? (p + lOff1) : infp;
            GLOAD_LDS(s1, &aS4[s][256 + wbase]);
        }
    }

    // Row-pair erode: 4 rows x 2 cols = 8 b128 -> 2 output chunks. Vertical
    // windows share min(a1,a2). P2_0/P1_0 = row0 D-chain, P2_1/P1_1 = row1.
    #define ERODE_SLICE(SLOT, ZPV, DO_E, ETI, P2_0, P1_0, P2_1, P1_1)              \
    do { if (isE) {                                                                \
        const float4* s_ = aS4[SLOT];                                              \
        float4 a0 = s_[eRdP],           b0 = s_[eRdP + 1];                         \
        float4 a1 = s_[eRdP + AW4],     b1 = s_[eRdP + AW4 + 1];                   \
        float4 a2 = s_[eRdP + 2 * AW4], b2 = s_[eRdP + 2 * AW4 + 1];               \
        float4 a3 = s_[eRdP + 3 * AW4], b3 = s_[eRdP + 3 * AW4 + 1];               \
        float4 ma;                                                                 \
        ma.x = fminf(a1.x, a2.x); ma.y = fminf(a1.y, a2.y);                        \
        ma.z = fminf(a1.z, a2.z); ma.w = fminf(a1.w, a2.w);                        \
        float4 v0a, v1a;                                                           \
        v0a.x = fminf(a0.x, ma.x); v0a.y = fminf(a0.y, ma.y);                      \
        v0a.z = fminf(a0.z, ma.z); v0a.w = fminf(a0.w, ma.w);                      \
        v1a.x = fminf(a3.x, ma.x); v1a.y = fminf(a3.y, ma.y);                      \
        v1a.z = fminf(a3.z, ma.z); v1a.w = fminf(a3.w, ma.w);                      \
        float mbx = fminf(b1.x, b2.x), mby = fminf(b1.y, b2.y), mbz = fminf(b1.z, b2.z); \
        float v0bx = fminf(b0.x, mbx), v0by = fminf(b0.y, mby), v0bz = fminf(b0.z, mbz); \
        float v1bx = fminf(b3.x, mbx), v1by = fminf(b3.y, mby), v1bz = fminf(b3.z, mbz); \
        float4 mC0, mC1;                                                           \
        mC0.x = min3f(v0a.y, v0a.z, v0a.w);                                        \
        mC0.y = min3f(v0a.z, v0a.w, v0bx);                                         \
        mC0.z = min3f(v0a.w, v0bx, v0by);                                          \
        mC0.w = min3f(v0bx, v0by, v0bz);                                           \
        mC1.x = min3f(v1a.y, v1a.z, v1a.w);                                        \
        mC1.y = min3f(v1a.z, v1a.w, v1bx);                                         \
        mC1.z = min3f(v1a.w, v1bx, v1by);                                          \
        mC1.w = min3f(v1bx, v1by, v1bz);                                           \
        if ((DO_E) && (ZPV)) {                                                     \
            float4 e;                                                              \
            e.x = s0A ? min3f(P2_0.x, P1_0.x, mC0.x) : -INF;                       \
            e.y = s0B ? min3f(P2_0.y, P1_0.y, mC0.y) : -INF;                       \
            e.z = s0C ? min3f(P2_0.z, P1_0.z, mC0.z) : -INF;                       \
            e.w = s0D ? min3f(P2_0.w, P1_0.w, mC0.w) : -INF;                       \
            eT4[ETI][eWrP] = e;                                                    \
            e.x = s1A ? min3f(P2_1.x, P1_1.x, mC1.x) : -INF;                       \
            e.y = s1B ? min3f(P2_1.y, P1_1.y, mC1.y) : -INF;                       \
            e.z = s1C ? min3f(P2_1.z, P1_1.z, mC1.z) : -INF;                       \
            e.w = s1D ? min3f(P2_1.w, P1_1.w, mC1.w) : -INF;                       \
            eT4[ETI][eWrP + EW4] = e;                                              \
        }                                                                          \
        P2_0 = P1_0; P1_0 = mC0; P2_1 = P1_1; P1_1 = mC1;                          \
    } } while (0)

    // DPP dilation: 3 own-column reads + divergent 17th-column reads on wq==15;
    // neighbor column's vertical max + raw center row via row_shl:1 DPP.
    // NOTE: dpp_shl1 must run in uniform control flow (all 256 lanes).
    #define MAX9(ETI, xCv, ecv)                                                    \
    do {                                                                           \
        const float4* eP_ = eT4[ETI];                                              \
        float4 A0 = eP_[oRd], A1 = eP_[oRd + EW4], A2 = eP_[oRd + 2 * EW4];        \
        float4 B0, B1, B2;                                                         \
        if (isB) {                                                                 \
            B0 = eP_[oRd + 1]; B1 = eP_[oRd + EW4 + 1]; B2 = eP_[oRd + 2 * EW4 + 1]; \
        }                                                                          \
        float4 vm;                                                                 \
        vm.x = max3f(A0.x, A1.x, A2.x); vm.y = max3f(A0.y, A1.y, A2.y);            \
        vm.z = max3f(A0.z, A1.z, A2.z); vm.w = max3f(A0.w, A1.w, A2.w);            \
        float sx = dpp_shl1(vm.x), sy = dpp_shl1(vm.y), sz = dpp_shl1(vm.z);       \
        float c1x = dpp_shl1(A1.x), c1y = dpp_shl1(A1.y);                          \
        float bvx = max3f(B0.x, B1.x, B2.x);                                       \
        float bvy = max3f(B0.y, B1.y, B2.y);                                       \
        float bvz = max3f(B0.z, B1.z, B2.z);                                       \
        float nbx = isB ? bvx : sx;                                                \
        float nby = isB ? bvy : sy;                                                \
        float nbz = isB ? bvz : sz;                                                \
        xCv.x = max3f(vm.y, vm.z, vm.w);                                           \
        xCv.y = max3f(vm.z, vm.w, nbx);                                            \
        xCv.z = max3f(vm.w, nbx, nby);                                             \
        xCv.w = max3f(nbx, nby, nbz);                                              \
        ecv.x = A1.z; ecv.y = A1.w;                                                \
        ecv.z = isB ? B1.x : c1x;                                                  \
        ecv.w = isB ? B1.y : c1y;                                                  \
    } while (0)

    for (int k = 0; k < (TDZ + 4) / 2; ++k) {
        const int i0 = 2 * k, i1 = 2 * k + 1;
        const int slot0 = i0 & 3, slot1 = i1 & 3;

        // B1: pair slices loaded. k<3: only gloads outstanding -> full drain.
        // k>=3: leave prior pair's stores (4; 2 at step 20) in flight.
        if (k < 3) { BAR_FULL(); }
        else if (step == NUM_ITER) { BAR_VM2(); }
        else { BAR_VM4(); }

        // early skel prefetch (oldest VMEM of the pair)
        float4 ggPre0, ggPre1;
        if (step > 0 && i0 >= 4) { ggPre0 = sk4[ob]; ggPre1 = sk4[ob + HW4]; }
        __builtin_amdgcn_sched_barrier(0);

        // issue next pair (slices 2k+2, 2k+3) into the opposite slots
        if (k <= (TDZ + 4) / 2 - 2) {
            for (int s = 0; s < 2; ++s) {
                int z = z0 + 2 * k + s;          // slice 2k+2+s -> z0-2+(2k+2+s)
                bool zok = (unsigned)z < D_DIM;
                const float* p = in + (size_t)z * HW;
                const float* s0 = (zok && lVal0) ? (p + lOff0) : infp;
                GLOAD_LDS(s0, &aS4[(i0 + 2 + s) & 3][wbase]);
                if (hasL1) {
                    const float* s1 = (zok && lVal1) ? (p + lOff1) : infp;
                    GLOAD_LDS(s1, &aS4[(i0 + 2 + s) & 3][256 + wbase]);
                }
            }
        }
        __builtin_amdgcn_sched_barrier(0);

        const bool zp0 = (unsigned)(z0 - 3 + i0) < D_DIM;
        const bool zp1 = (unsigned)(z0 - 3 + i1) < D_DIM;
        const bool doE = (i0 >= 2);

        // ---- erode both slices -> eT4[0], eT4[1] ----
        ERODE_SLICE(slot0, zp0, doE, 0, m0P2, m0P1, m1P2, m1P1);
        ERODE_SLICE(slot1, zp1, (i1 >= 2), 1, m0P2, m0P1, m1P2, m1P1);

        // a-centers for both slices (issued pre-B2; aS4 pair stable)
        const float4 aCn0 = aS4[slot0][oAc];
        const float4 aCn1 = aS4[slot1][oAc];

        BAR_LDS();  // B2: eT4 ready (vmcnt NOT drained — next pair in flight)

        // ---- out both slices ----
        {
            float4 xC0, ecB0, xC1, ecB1;
            if (doE && zp0) { MAX9(0, xC0, ecB0); } else { xC0 = ninf4; ecB0 = ninf4; }
            if (doE && zp1) { MAX9(1, xC1, ecB1); } else { xC1 = ninf4; ecB1 = ninf4; }

            if (i0 >= 4) {
                {
                    float4 dl;
                    dl.x = leaky(acP2.x - max3f(xP2.x, xP1.x, xC0.x));
                    dl.y = leaky(acP2.y - max3f(xP2.y, xP1.y, xC0.y));
                    dl.z = leaky(acP2.z - max3f(xP2.z, xP1.z, xC0.z));
                    dl.w = leaky(acP2.w - max3f(xP2.w, xP1.w, xC0.w));
                    if (step < NUM_ITER) aout4[ob] = ecP;
                    if (step == 0) {
                        sk4[ob] = dl;
                    } else {
                        float4 gg = ggPre0, up, gn;
                        up.x = leaky(dl.x - gg.x * dl.x); gn.x = gg.x + up.x;
                        up.y = leaky(dl.y - gg.y * dl.y); gn.y = gg.y + up.y;
                        up.z = leaky(dl.z - gg.z * dl.z); gn.z = gg.z + up.z;
                        up.w = leaky(dl.w - gg.w * dl.w); gn.w = gg.w + up.w;
                        sk4[ob] = gn;
                        if (step == 1)
                            lsum += fabsf(gn.x) + fabsf(gn.y) + fabsf(gn.z) + fabsf(gn.w);
                        else
                            lsum += fabsf(up.x) + fabsf(up.y) + fabsf(up.z) + fabsf(up.w);
                    }
                }
                {
                    float4 dl;
                    dl.x = leaky(acP1.x - max3f(xP1.x, xC0.x, xC1.x));
                    dl.y = leaky(acP1.y - max3f(xP1.y, xC0.y, xC1.y));
                    dl.z = leaky(acP1.z - max3f(xP1.z, xC0.z, xC1.z));
                    dl.w = leaky(acP1.w - max3f(xP1.w, xC0.w, xC1.w));
                    if (step < NUM_ITER) aout4[ob + HW4] = ecB0;
                    if (step == 0) {
                        sk4[ob + HW4] = dl;
                    } else {
                        float4 gg = ggPre1, up, gn;
                        up.x = leaky(dl.x - gg.x * dl.x); gn.x = gg.x + up.x;
                        up.y = leaky(dl.y - gg.y * dl.y); gn.y = gg.y + up.y;
                        up.z = leaky(dl.z - gg.z * dl.z); gn.z = gg.z + up.z;
                        up.w = leaky(dl.w - gg.w * dl.w); gn.w = gg.w + up.w;
                        sk4[ob + HW4] = gn;
                        if (step == 1)
                            lsum += fabsf(gn.x) + fabsf(gn.y) + fabsf(gn.z) + fabsf(gn.w);
                        else
                            lsum += fabsf(up.x) + fabsf(up.y) + fabsf(up.z) + fabsf(up.w);
                    }
                }
                ob += 2 * HW4;
            }
            xP2 = xC0; xP1 = xC1;
            acP2 = aCn0; acP1 = aCn1;
            ecP = ecB1;
        }
    }

    #undef ERODE_SLICE
    #undef MAX9

    // dn reduction: one double atomic per block
    if (step > 0) {
        #pragma unroll
        for (int off = 32; off > 0; off >>= 1)
            lsum += __shfl_down(lsum, off, 64);
        const int lane = t & 63, wid = t >> 6;
        if (lane == 0) wsum[wid] = lsum;
        __syncthreads();
        if (t == 0) {
            float b = wsum[0] + wsum[1] + wsum[2] + wsum[3];
            atomicAdd(&slots[step], (double)b);
        }
    }
}

extern "C" void kernel_launch(void* const* d_in, const int* in_sizes, int n_in,
                              void* d_out, int out_size, void* d_ws, size_t ws_size,
                              hipStream_t stream) {
    const float* img = (const float*)d_in[0];
    float* out = (float*)d_out;
    float* buf0 = (float*)d_ws;
    float* buf1 = buf0 + NTOT;
    double* slots = (double*)(buf1 + NTOT);

    init_slots<<<1, 64, 0, stream>>>(slots);

    dim3 grid(W_DIM / TW, H_DIM / TH, (D_DIM / TDZ) * NIMG);
    for (int s = 0; s <= NUM_ITER; ++s) {
        const float* ain = (s == 0) ? img : ((s & 1) ? buf0 : buf1);
        float* aout = (s & 1) ? buf1 : buf0;
        skel_step<<<grid, 256, 0, stream>>>(ain, aout, out, slots, s);
    }
}

// Round 21
// 324.618 us; speedup vs baseline: 1.1251x; 1.0231x over previous
//
#include <hip/hip_runtime.h>
#include <math.h>

#define D_DIM 128
#define H_DIM 256
#define W_DIM 256
#define HW (H_DIM * W_DIM)
#define HW4 (HW / 4)
#define NIMG 2
#define NPI (D_DIM * HW)
#define NTOT (NIMG * NPI)

#define TDZ 32
#define TH 16
#define TW 64

#define AW4R 18  // real aS chunks/row: chunk c -> gx = x0-4+4c (x0-4 .. x0+67)
#define AW4 19   // padded aS row stride
#define AH 20    // aS rows: gy = y0-2 .. y0+17
#define EW4R 17  // real eT chunks/row: chunk c -> gx = x0-2+4c (x0-2 .. x0+65)
#define EW4 19   // padded eT row stride
#define EH 18    // eT rows: gy = y0-1 .. y0+16

#define NLOADLIN (AH * AW4)   // 380 padded-linear load slots
#define NLOADP 384            // rounded to 6 full waves
#define NEPAIR ((EH / 2) * EW4R)  // 153 row-pair erode items

#define NUM_ITER 20
#define STOP_THRESH 1e-4

__device__ __forceinline__ float min3f(float a, float b, float c) { return fminf(fminf(a, b), c); }
__device__ __forceinline__ float max3f(float a, float b, float c) { return fmaxf(fmaxf(a, b), c); }
__device__ __forceinline__ float leaky(float x) { return fmaxf(x, 0.01f * x); }

// lane L receives lane L+1's value within each 16-lane DPP row (row_shl:1).
// Must be executed by ALL lanes (uniform control flow) so source data exists.
__device__ __forceinline__ float dpp_shl1(float v) {
    int i = __float_as_int(v);
    int r = __builtin_amdgcn_update_dpp(i, i, 0x101, 0xF, 0xF, false);
    return __int_as_float(r);
}

// B1 variants: drain gloads but leave prior-pair stores in flight where safe.
#define BAR_FULL() do { asm volatile("s_waitcnt vmcnt(0) lgkmcnt(0)" ::: "memory"); \
                        __builtin_amdgcn_s_barrier(); \
                        __builtin_amdgcn_sched_barrier(0); } while (0)
#define BAR_VM4()  do { asm volatile("s_waitcnt vmcnt(4) lgkmcnt(0)" ::: "memory"); \
                        __builtin_amdgcn_s_barrier(); \
                        __builtin_amdgcn_sched_barrier(0); } while (0)
#define BAR_VM2()  do { asm volatile("s_waitcnt vmcnt(2) lgkmcnt(0)" ::: "memory"); \
                        __builtin_amdgcn_s_barrier(); \
                        __builtin_amdgcn_sched_barrier(0); } while (0)
// B2: LDS-only drain — keeps global_load_lds for the next pair in flight
#define BAR_LDS() do { asm volatile("s_waitcnt lgkmcnt(0)" ::: "memory"); \
                       __builtin_amdgcn_s_barrier(); \
                       __builtin_amdgcn_sched_barrier(0); } while (0)

#define GLOAD_LDS(gp, lp) \
    __builtin_amdgcn_global_load_lds((const __attribute__((address_space(1))) unsigned int*)(gp), \
                                     (__attribute__((address_space(3))) unsigned int*)(lp), 16, 0, 0)

__global__ void init_slots(double* slots) {
    int t = threadIdx.x;
    if (t < 32) slots[t] = 0.0;
    if (t >= 32 && t < 36) ((float*)(slots + 32))[t - 32] = INFINITY;  // 16B +INF cell
}

// R20 structure (row-pair erode + DPP dilation), TDZ 16->32: 36 iterations per
// 32 outputs (fill amortization 1.125x vs 1.25x), grid 512 blocks = 2/CU.
__global__ __launch_bounds__(256) void skel_step(
    const float* __restrict__ a_in,
    float* __restrict__ a_out,
    float* __restrict__ skel,
    double* __restrict__ slots,
    int step)
{
    __shared__ float4 aS4[4][NLOADP];  // 24576 B (4 slice slots, gload dest)
    __shared__ float4 eT4[2][EH * EW4];// 10944 B (padded rows)
    __shared__ float wsum[4];

    const int t = threadIdx.x;

    // gating: uniform per-thread check (slots[] reads are scalar/L2-cached)
    {
        int act = 1;
        for (int j = 1; j < step; ++j)
            if (!(slots[j] >= STOP_THRESH * (double)NTOT)) { act = 0; break; }
        if (!act) return;
    }

    const float* infp = (const float*)(slots + 32);

    // XCD-aware swizzle: grid (4,16,8) = 512 blocks; XCD k owns swz in
    // [64k,64(k+1)) = full xy coverage of 1 z-slab.
    const int lid = blockIdx.x + 4 * (blockIdx.y + 16 * blockIdx.z);
    const int swz = (lid & 7) * 64 + (lid >> 3);
    const int bx = swz & 3;
    const int by = (swz >> 2) & 15;
    const int zz = swz >> 6;           // 0..7
    const int bz = zz & 3, img = zz >> 2;
    const int x0 = bx * TW, y0 = by * TH, z0 = bz * TDZ;

    const float* in = a_in + (size_t)img * NPI;
    float4* aout4 = (float4*)(a_out + (size_t)img * NPI);
    float4* sk4 = (float4*)(skel + (size_t)img * NPI);

    // ---- load items in PADDED-linear order: q0 = t, q1 = t+256 (t<128) ----
    int lOff0; bool lVal0;
    {
        int lr = t / AW4, lc = t - lr * AW4;
        int gy = y0 - 2 + lr, gx = x0 - 4 + 4 * lc;
        lVal0 = (lc < AW4R) && ((unsigned)gy < H_DIM) && ((unsigned)gx <= (unsigned)(W_DIM - 4));
        lOff0 = gy * W_DIM + gx;
    }
    const bool hasL1 = t < 128;          // wave-uniform
    int lOff1 = 0; bool lVal1 = false;
    if (hasL1) {
        int q = t + 256;
        int lr = q / AW4, lc = q - lr * AW4;
        int gy = y0 - 2 + lr, gx = x0 - 4 + 4 * lc;
        lVal1 = (q < NLOADLIN) && (lc < AW4R) && ((unsigned)gy < H_DIM)
                && ((unsigned)gx <= (unsigned)(W_DIM - 4));
        lOff1 = gy * W_DIM + gx;
    }
    const int wbase = (t >> 6) << 6;     // wave-uniform LDS base (element units)

    // ---- erode items: row-pair (rp, ej), t = rp*17 + ej, t < 153 ----
    const bool isE = t < NEPAIR;
    int eRdP = 0, eWrP = 0;
    bool s0A = false, s0B = false, s0C = false, s0D = false;
    bool s1A = false, s1B = false, s1C = false, s1D = false;
    if (isE) {
        int rp = t / EW4R, ej = t - rp * EW4R;
        int mh0 = 2 * rp;               // eT rows mh0, mh0+1
        eRdP = mh0 * AW4 + ej;          // aS rows mh0..mh0+3, cols ej, ej+1
        eWrP = mh0 * EW4 + ej;
        int gy0e = y0 - 1 + mh0;
        bool g0 = (unsigned)gy0e < H_DIM;
        bool g1 = (unsigned)(gy0e + 1) < H_DIM;
        int gxb = x0 - 2 + 4 * ej;
        bool xA = (unsigned)(gxb + 0) < W_DIM;
        bool xB = (unsigned)(gxb + 1) < W_DIM;
        bool xC = (unsigned)(gxb + 2) < W_DIM;
        bool xD = (unsigned)(gxb + 3) < W_DIM;
        s0A = g0 && xA; s0B = g0 && xB; s0C = g0 && xC; s0D = g0 && xD;
        s1A = g1 && xA; s1B = g1 && xB; s1C = g1 && xC; s1D = g1 && xD;
    }

    // ---- out item ----
    const int oh = t >> 4, wq = t & 15;
    const bool isB = (wq == 15);         // boundary lane: owns the 17th column
    const int oRd = oh * EW4 + wq;
    const int oAc = (oh + 2) * AW4 + wq + 1;
    size_t ob = ((size_t)z0 * HW + (size_t)(y0 + oh) * W_DIM + (size_t)x0) / 4 + wq;

    const float INF = INFINITY;
    const float4 ninf4 = make_float4(-INF, -INF, -INF, -INF);
    const float4 inf4 = make_float4(INF, INF, INF, INF);
    // rolling D-chains: row0 (m0*) and row1 (m1*) of the pair; advance per slice
    float4 m0P2 = inf4, m0P1 = inf4, m1P2 = inf4, m1P1 = inf4;
    float4 xP2 = ninf4, xP1 = ninf4;
    float4 acP2 = make_float4(0, 0, 0, 0), acP1 = acP2, ecP = acP2;
    float lsum = 0.f;

    // ---- prologue: issue slices 0,1 into slots 0,1 ----
    for (int s = 0; s < 2; ++s) {
        int z = z0 - 2 + s;
        bool zok = (unsigned)z < D_DIM;
        const float* p = in + (size_t)z * HW;
        const float* s0 = (zok && lVal0) ? (p + lOff0) : infp;
        GLOAD_LDS(s0, &aS4[s][wbase]);
        if (hasL1) {
            const float* s1 = (zok && lVal1) ? (p + lOff1) : infp;
            GLOAD_LDS(s1, &aS4[s][256 + wbase]);
        }
    }

    // Row-pair erode: 4 rows x 2 cols = 8 b128 -> 2 output chunks. Vertical
    // windows share min(a1,a2). P2_0/P1_0 = row0 D-chain, P2_1/P1_1 = row1.
    #define ERODE_SLICE(SLOT, ZPV, DO_E, ETI, P2_0, P1_0, P2_1, P1_1)              \
    do { if (isE) {                                                                \
        const float4* s_ = aS4[SLOT];                                              \
        float4 a0 = s_[eRdP],           b0 = s_[eRdP + 1];                         \
        float4 a1 = s_[eRdP + AW4],     b1 = s_[eRdP + AW4 + 1];                   \
        float4 a2 = s_[eRdP + 2 * AW4], b2 = s_[eRdP + 2 * AW4 + 1];               \
        float4 a3 = s_[eRdP + 3 * AW4], b3 = s_[eRdP + 3 * AW4 + 1];               \
        float4 ma;                                                                 \
        ma.x = fminf(a1.x, a2.x); ma.y = fminf(a1.y, a2.y);                        \
        ma.z = fminf(a1.z, a2.z); ma.w = fminf(a1.w, a2.w);                        \
        float4 v0a, v1a;                                                           \
        v0a.x = fminf(a0.x, ma.x); v0a.y = fminf(a0.y, ma.y);                      \
        v0a.z = fminf(a0.z, ma.z); v0a.w = fminf(a0.w, ma.w);                      \
        v1a.x = fminf(a3.x, ma.x); v1a.y = fminf(a3.y, ma.y);                      \
        v1a.z = fminf(a3.z, ma.z); v1a.w = fminf(a3.w, ma.w);                      \
        float mbx = fminf(b1.x, b2.x), mby = fminf(b1.y, b2.y), mbz = fminf(b1.z, b2.z); \
        float v0bx = fminf(b0.x, mbx), v0by = fminf(b0.y, mby), v0bz = fminf(b0.z, mbz); \
        float v1bx = fminf(b3.x, mbx), v1by = fminf(b3.y, mby), v1bz = fminf(b3.z, mbz); \
        float4 mC0, mC1;                                                           \
        mC0.x = min3f(v0a.y, v0a.z, v0a.w);                                        \
        mC0.y = min3f(v0a.z, v0a.w, v0bx);                                         \
        mC0.z = min3f(v0a.w, v0bx, v0by);                                          \
        mC0.w = min3f(v0bx, v0by, v0bz);                                           \
        mC1.x = min3f(v1a.y, v1a.z, v1a.w);                                        \
        mC1.y = min3f(v1a.z, v1a.w, v1bx);                                         \
        mC1.z = min3f(v1a.w, v1bx, v1by);                                          \
        mC1.w = min3f(v1bx, v1by, v1bz);                                           \
        if ((DO_E) && (ZPV)) {                                                     \
            float4 e;                                                              \
            e.x = s0A ? min3f(P2_0.x, P1_0.x, mC0.x) : -INF;                       \
            e.y = s0B ? min3f(P2_0.y, P1_0.y, mC0.y) : -INF;                       \
            e.z = s0C ? min3f(P2_0.z, P1_0.z, mC0.z) : -INF;                       \
            e.w = s0D ? min3f(P2_0.w, P1_0.w, mC0.w) : -INF;                       \
            eT4[ETI][eWrP] = e;                                                    \
            e.x = s1A ? min3f(P2_1.x, P1_1.x, mC1.x) : -INF;                       \
            e.y = s1B ? min3f(P2_1.y, P1_1.y, mC1.y) : -INF;                       \
            e.z = s1C ? min3f(P2_1.z, P1_1.z, mC1.z) : -INF;                       \
            e.w = s1D ? min3f(P2_1.w, P1_1.w, mC1.w) : -INF;                       \
            eT4[ETI][eWrP + EW4] = e;                                              \
        }                                                                          \
        P2_0 = P1_0; P1_0 = mC0; P2_1 = P1_1; P1_1 = mC1;                          \
    } } while (0)

    // DPP dilation: 3 own-column reads + divergent 17th-column reads on wq==15;
    // neighbor column's vertical max + raw center row via row_shl:1 DPP.
    // NOTE: dpp_shl1 must run in uniform control flow (all 256 lanes).
    #define MAX9(ETI, xCv, ecv)                                                    \
    do {                                                                           \
        const float4* eP_ = eT4[ETI];                                              \
        float4 A0 = eP_[oRd], A1 = eP_[oRd + EW4], A2 = eP_[oRd + 2 * EW4];        \
        float4 B0, B1, B2;                                                         \
        if (isB) {                                                                 \
            B0 = eP_[oRd + 1]; B1 = eP_[oRd + EW4 + 1]; B2 = eP_[oRd + 2 * EW4 + 1]; \
        }                                                                          \
        float4 vm;                                                                 \
        vm.x = max3f(A0.x, A1.x, A2.x); vm.y = max3f(A0.y, A1.y, A2.y);            \
        vm.z = max3f(A0.z, A1.z, A2.z); vm.w = max3f(A0.w, A1.w, A2.w);            \
        float sx = dpp_shl1(vm.x), sy = dpp_shl1(vm.y), sz = dpp_shl1(vm.z);       \
        float c1x = dpp_shl1(A1.x), c1y = dpp_shl1(A1.y);                          \
        float bvx = max3f(B0.x, B1.x, B2.x);                                       \
        float bvy = max3f(B0.y, B1.y, B2.y);                                       \
        float bvz = max3f(B0.z, B1.z, B2.z);                                       \
        float nbx = isB ? bvx : sx;                                                \
        float nby = isB ? bvy : sy;                                                \
        float nbz = isB ? bvz : sz;                                                \
        xCv.x = max3f(vm.y, vm.z, vm.w);                                           \
        xCv.y = max3f(vm.z, vm.w, nbx);                                            \
        xCv.z = max3f(vm.w, nbx, nby);                                             \
        xCv.w = max3f(nbx, nby, nbz);                                              \
        ecv.x = A1.z; ecv.y = A1.w;                                                \
        ecv.z = isB ? B1.x : c1x;                                                  \
        ecv.w = isB ? B1.y : c1y;                                                  \
    } while (0)

    for (int k = 0; k < (TDZ + 4) / 2; ++k) {
        const int i0 = 2 * k, i1 = 2 * k + 1;
        const int slot0 = i0 & 3, slot1 = i1 & 3;

        // B1: pair slices loaded. k<3: only gloads outstanding -> full drain.
        // k>=3: leave prior pair's stores (4; 2 at step 20) in flight.
        if (k < 3) { BAR_FULL(); }
        else if (step == NUM_ITER) { BAR_VM2(); }
        else { BAR_VM4(); }

        // early skel prefetch (oldest VMEM of the pair)
        float4 ggPre0, ggPre1;
        if (step > 0 && i0 >= 4) { ggPre0 = sk4[ob]; ggPre1 = sk4[ob + HW4]; }
        __builtin_amdgcn_sched_barrier(0);

        // issue next pair (slices 2k+2, 2k+3) into the opposite slots
        if (k <= (TDZ + 4) / 2 - 2) {
            for (int s = 0; s < 2; ++s) {
                int z = z0 + 2 * k + s;          // slice 2k+2+s -> z0-2+(2k+2+s)
                bool zok = (unsigned)z < D_DIM;
                const float* p = in + (size_t)z * HW;
                const float* s0 = (zok && lVal0) ? (p + lOff0) : infp;
                GLOAD_LDS(s0, &aS4[(i0 + 2 + s) & 3][wbase]);
                if (hasL1) {
                    const float* s1 = (zok && lVal1) ? (p + lOff1) : infp;
                    GLOAD_LDS(s1, &aS4[(i0 + 2 + s) & 3][256 + wbase]);
                }
            }
        }
        __builtin_amdgcn_sched_barrier(0);

        const bool zp0 = (unsigned)(z0 - 3 + i0) < D_DIM;
        const bool zp1 = (unsigned)(z0 - 3 + i1) < D_DIM;
        const bool doE = (i0 >= 2);

        // ---- erode both slices -> eT4[0], eT4[1] ----
        ERODE_SLICE(slot0, zp0, doE, 0, m0P2, m0P1, m1P2, m1P1);
        ERODE_SLICE(slot1, zp1, (i1 >= 2), 1, m0P2, m0P1, m1P2, m1P1);

        // a-centers for both slices (issued pre-B2; aS4 pair stable)
        const float4 aCn0 = aS4[slot0][oAc];
        const float4 aCn1 = aS4[slot1][oAc];

        BAR_LDS();  // B2: eT4 ready (vmcnt NOT drained — next pair in flight)

        // ---- out both slices ----
        {
            float4 xC0, ecB0, xC1, ecB1;
            if (doE && zp0) { MAX9(0, xC0, ecB0); } else { xC0 = ninf4; ecB0 = ninf4; }
            if (doE && zp1) { MAX9(1, xC1, ecB1); } else { xC1 = ninf4; ecB1 = ninf4; }

            if (i0 >= 4) {
                {
                    float4 dl;
                    dl.x = leaky(acP2.x - max3f(xP2.x, xP1.x, xC0.x));
                    dl.y = leaky(acP2.y - max3f(xP2.y, xP1.y, xC0.y));
                    dl.z = leaky(acP2.z - max3f(xP2.z, xP1.z, xC0.z));
                    dl.w = leaky(acP2.w - max3f(xP2.w, xP1.w, xC0.w));
                    if (step < NUM_ITER) aout4[ob] = ecP;
                    if (step == 0) {
                        sk4[ob] = dl;
                    } else {
                        float4 gg = ggPre0, up, gn;
                        up.x = leaky(dl.x - gg.x * dl.x); gn.x = gg.x + up.x;
                        up.y = leaky(dl.y - gg.y * dl.y); gn.y = gg.y + up.y;
                        up.z = leaky(dl.z - gg.z * dl.z); gn.z = gg.z + up.z;
                        up.w = leaky(dl.w - gg.w * dl.w); gn.w = gg.w + up.w;
                        sk4[ob] = gn;
                        if (step == 1)
                            lsum += fabsf(gn.x) + fabsf(gn.y) + fabsf(gn.z) + fabsf(gn.w);
                        else
                            lsum += fabsf(up.x) + fabsf(up.y) + fabsf(up.z) + fabsf(up.w);
                    }
                }
                {
                    float4 dl;
                    dl.x = leaky(acP1.x - max3f(xP1.x, xC0.x, xC1.x));
                    dl.y = leaky(acP1.y - max3f(xP1.y, xC0.y, xC1.y));
                    dl.z = leaky(acP1.z - max3f(xP1.z, xC0.z, xC1.z));
                    dl.w = leaky(acP1.w - max3f(xP1.w, xC0.w, xC1.w));
                    if (step < NUM_ITER) aout4[ob + HW4] = ecB0;
                    if (step == 0) {
                        sk4[ob + HW4] = dl;
                    } else {
                        float4 gg = ggPre1, up, gn;
                        up.x = leaky(dl.x - gg.x * dl.x); gn.x = gg.x + up.x;
                        up.y = leaky(dl.y - gg.y * dl.y); gn.y = gg.y + up.y;
                        up.z = leaky(dl.z - gg.z * dl.z); gn.z = gg.z + up.z;
                        up.w = leaky(dl.w - gg.w * dl.w); gn.w = gg.w + up.w;
                        sk4[ob + HW4] = gn;
                        if (step == 1)
                            lsum += fabsf(gn.x) + fabsf(gn.y) + fabsf(gn.z) + fabsf(gn.w);
                        else
                            lsum += fabsf(up.x) + fabsf(up.y) + fabsf(up.z) + fabsf(up.w);
                    }
                }
                ob += 2 * HW4;
            }
            xP2 = xC0; xP1 = xC1;
            acP2 = aCn0; acP1 = aCn1;
            ecP = ecB1;
        }
    }

    #undef ERODE_SLICE
    #undef MAX9

    // dn reduction: one double atomic per block
    if (step > 0) {
        #pragma unroll
        for (int off = 32; off > 0; off >>= 1)
            lsum += __shfl_down(lsum, off, 64);
        const int lane = t & 63, wid = t >> 6;
        if (lane == 0) wsum[wid] = lsum;
        __syncthreads();
        if (t == 0) {
            float b = wsum[0] + wsum[1] + wsum[2] + wsum[3];
            atomicAdd(&slots[step], (double)b);
        }
    }
}

extern "C" void kernel_launch(void* const* d_in, const int* in_sizes, int n_in,
                              void* d_out, int out_size, void* d_ws, size_t ws_size,
                              hipStream_t stream) {
    const float* img = (const float*)d_in[0];
    float* out = (float*)d_out;
    float* buf0 = (float*)d_ws;
    float* buf1 = buf0 + NTOT;
    double* slots = (double*)(buf1 + NTOT);

    init_slots<<<1, 64, 0, stream>>>(slots);

    dim3 grid(W_DIM / TW, H_DIM / TH, (D_DIM / TDZ) * NIMG);
    for (int s = 0; s <= NUM_ITER; ++s) {
        const float* ain = (s == 0) ? img : ((s & 1) ? buf0 : buf1);
        float* aout = (s & 1) ? buf1 : buf0;
        skel_step<<<grid, 256, 0, stream>>>(ain, aout, out, slots, s);
    }
}